// Round 5
// baseline (114.322 us; speedup 1.0000x reference)
//
#include <hip/hip_runtime.h>
#include <hip/hip_cooperative_groups.h>
#include <math.h>

#define B_DIM    1024
#define IN_DIMS  512
#define OUT_DIMS 512
#define MOD_DIM  256
#define EPS_F    1e-8f

#define LPB 264   // phase-B LDS row stride (bf16 elems): 528B -> bank step 4, 2-way (free)
#define LPC 520   // phase-C LDS row stride: 1040B -> bank step 4, 2-way (free)

typedef __attribute__((ext_vector_type(8))) short bf16x8;
typedef __attribute__((ext_vector_type(4))) float f32x4;
typedef unsigned short ush;

namespace cg = cooperative_groups;

__device__ __forceinline__ ush f2bf(float f) {
    union { float f; unsigned u; } c; c.f = f;
    unsigned r = c.u + 0x7fffu + ((c.u >> 16) & 1u);   // RNE
    return (ush)(r >> 16);
}
__device__ __forceinline__ float bf2f(ush h) {
    union { float f; unsigned u; } c; c.u = ((unsigned)h) << 16;
    return c.f;
}

// ---------------------------------------------------------------------------
// ONE fused kernel, cooperative, 256 blocks (1/CU) x 256 thr.
// Phase B (= round-4 k1): per-block colsum (64 cols), inline hi/lo split of
//   mods/mod_w, split-bf16 mod-GEMM (hh+hl+lh), demod epilogue -> t_bf.
// grid.sync()  (device-scope fence: t_bf visible across XCDs)
// Phase C (= round-4 k2): out = t_bf @ bf16(weight)^T + bias, weight
//   converted inline per block.
// LDS aliased between phases: max 105.7 KB -> 1 block/CU (= coop capacity).
// ---------------------------------------------------------------------------
__global__ __launch_bounds__(256) void fused_all(
    const float* __restrict__ mods,    // [1024,256]
    const float* __restrict__ x,       // [1024,512]
    const float* __restrict__ weight,  // [512,512]
    const float* __restrict__ bias,    // [512]
    const float* __restrict__ mod_w,   // [512,256]
    const float* __restrict__ mod_b,   // [512]
    ush* __restrict__ t_bf,            // ws [1024,512]
    float* __restrict__ out)           // [1024,512]
{
    __shared__ __align__(16) char smem[105728];
    // phase-B aliases
    ush* Ah = (ush*)smem;              // 32*LPB
    ush* Al = Ah + 32 * LPB;           // 32*LPB
    ush* Bh = Al + 32 * LPB;           // 64*LPB
    ush* Bl = Bh + 64 * LPB;           // 64*LPB  (ends at byte 101376)
    float4* csm    = (float4*)(smem + 101376);   // 16x16 float4 = 4096B
    float*  colsum = (float*)(smem + 105472);    // 64 floats
    // phase-C aliases
    ush* As = (ush*)smem;              // 32*LPC (33280B)
    ush* Bs = As + 32 * LPC;           // 64*LPC (66560B, ends 99840)

    const int tid = threadIdx.x;
    const int n0 = blockIdx.x * 64;    // 8 n-tiles
    const int m0 = blockIdx.y * 32;    // 32 m-tiles
    const int lane = tid & 63, wv = tid >> 6;
    const int wm = (wv >> 1) * 16, wn = (wv & 1) * 32;
    const int lr = lane & 15, lq = lane >> 4;

    // ======================= Phase B: mod GEMM -> t_bf =======================
    // stage A (mods 32x256), hi/lo split: 8 float4/thread
    #pragma unroll
    for (int i = 0; i < 8; i++) {
        const int id = tid + i * 256;
        const int r = id >> 6, c4 = id & 63;
        float4 v = *(const float4*)&mods[(m0 + r) * MOD_DIM + c4 * 4];
        ushort4 h, l;
        h.x = f2bf(v.x); l.x = f2bf(v.x - bf2f(h.x));
        h.y = f2bf(v.y); l.y = f2bf(v.y - bf2f(h.y));
        h.z = f2bf(v.z); l.z = f2bf(v.z - bf2f(h.z));
        h.w = f2bf(v.w); l.w = f2bf(v.w - bf2f(h.w));
        *(ushort4*)&Ah[r * LPB + c4 * 4] = h;
        *(ushort4*)&Al[r * LPB + c4 * 4] = l;
    }
    // stage B (mod_w 64x256), hi/lo split: 16 float4/thread
    #pragma unroll
    for (int i = 0; i < 16; i++) {
        const int id = tid + i * 256;
        const int r = id >> 6, c4 = id & 63;
        float4 v = *(const float4*)&mod_w[(n0 + r) * MOD_DIM + c4 * 4];
        ushort4 h, l;
        h.x = f2bf(v.x); l.x = f2bf(v.x - bf2f(h.x));
        h.y = f2bf(v.y); l.y = f2bf(v.y - bf2f(h.y));
        h.z = f2bf(v.z); l.z = f2bf(v.z - bf2f(h.z));
        h.w = f2bf(v.w); l.w = f2bf(v.w - bf2f(h.w));
        *(ushort4*)&Bh[r * LPB + c4 * 4] = h;
        *(ushort4*)&Bl[r * LPB + c4 * 4] = l;
    }
    // per-block colsum of this block's 64 columns (coalesced float4 rounds)
    {
        const int c4 = tid & 15, rr = tid >> 4;
        float4 acc = {0.f, 0.f, 0.f, 0.f};
        #pragma unroll
        for (int it = 0; it < 32; it++) {
            const int row = rr + 16 * it;
            float4 v = *(const float4*)&weight[row * IN_DIMS + n0 + c4 * 4];
            acc.x += v.x * v.x; acc.y += v.y * v.y;
            acc.z += v.z * v.z; acc.w += v.w * v.w;
        }
        csm[rr * 16 + c4] = acc;
    }
    __syncthreads();
    if (tid < 16) {
        float4 s = csm[tid];
        #pragma unroll
        for (int j = 1; j < 16; j++) {
            float4 v = csm[j * 16 + tid];
            s.x += v.x; s.y += v.y; s.z += v.z; s.w += v.w;
        }
        *(float4*)&colsum[tid * 4] = s;
    }

    f32x4 acc[2] = {};
    #pragma unroll
    for (int kk = 0; kk < 256; kk += 32) {
        const int ko = kk + lq * 8;
        bf16x8 ah  = *(bf16x8*)&Ah[(wm + lr) * LPB + ko];
        bf16x8 al  = *(bf16x8*)&Al[(wm + lr) * LPB + ko];
        bf16x8 bh0 = *(bf16x8*)&Bh[(wn +      lr) * LPB + ko];
        bf16x8 bh1 = *(bf16x8*)&Bh[(wn + 16 + lr) * LPB + ko];
        bf16x8 bl0 = *(bf16x8*)&Bl[(wn +      lr) * LPB + ko];
        bf16x8 bl1 = *(bf16x8*)&Bl[(wn + 16 + lr) * LPB + ko];
        acc[0] = __builtin_amdgcn_mfma_f32_16x16x32_bf16(ah, bh0, acc[0], 0, 0, 0);
        acc[1] = __builtin_amdgcn_mfma_f32_16x16x32_bf16(ah, bh1, acc[1], 0, 0, 0);
        acc[0] = __builtin_amdgcn_mfma_f32_16x16x32_bf16(ah, bl0, acc[0], 0, 0, 0);
        acc[1] = __builtin_amdgcn_mfma_f32_16x16x32_bf16(ah, bl1, acc[1], 0, 0, 0);
        acc[0] = __builtin_amdgcn_mfma_f32_16x16x32_bf16(al, bh0, acc[0], 0, 0, 0);
        acc[1] = __builtin_amdgcn_mfma_f32_16x16x32_bf16(al, bh1, acc[1], 0, 0, 0);
    }
    __syncthreads();   // colsum visibility within block

    // epilogue: s -> t = x*s*rsqrt(s^2*colsum+eps) -> bf16
    // C/D layout: col = lane&15, row = (lane>>4)*4 + reg
    #pragma unroll
    for (int j = 0; j < 2; j++) {
        const int ln = wn + 16 * j + lr;
        const int gn = n0 + ln;
        const float cs = colsum[ln];
        const float mb = mod_b[gn];
        #pragma unroll
        for (int rr = 0; rr < 4; rr++) {
            const int gm = m0 + wm + lq * 4 + rr;
            const float s = acc[j][rr] + mb;
            const float tv = x[gm * IN_DIMS + gn] * s * rsqrtf(s * s * cs + EPS_F);
            t_bf[gm * IN_DIMS + gn] = f2bf(tv);
        }
    }

    // =================== grid-wide sync: t_bf device-visible =================
    cg::this_grid().sync();

    // ======================= Phase C: out GEMM ==============================
    // stage A (t_bf 32x512 bf16): 8 uint4 copies/thread
    #pragma unroll
    for (int i = 0; i < 8; i++) {
        const int id = tid + i * 256;
        const int r = id >> 6, c8 = id & 63;
        *(uint4*)&As[r * LPC + c8 * 8] =
            *(const uint4*)&t_bf[(m0 + r) * IN_DIMS + c8 * 8];
    }
    // stage B (weight 64x512 fp32 -> bf16): 32 float4/thread
    #pragma unroll
    for (int i = 0; i < 32; i++) {
        const int id = tid + i * 256;
        const int r = id >> 7, c4 = id & 127;
        float4 v = *(const float4*)&weight[(n0 + r) * IN_DIMS + c4 * 4];
        ushort4 h;
        h.x = f2bf(v.x); h.y = f2bf(v.y); h.z = f2bf(v.z); h.w = f2bf(v.w);
        *(ushort4*)&Bs[r * LPC + c4 * 4] = h;
    }
    __syncthreads();

    f32x4 acc2[2] = {};
    #pragma unroll
    for (int kk = 0; kk < 512; kk += 32) {
        const int ko = kk + lq * 8;
        bf16x8 a  = *(bf16x8*)&As[(wm + lr) * LPC + ko];
        bf16x8 b0 = *(bf16x8*)&Bs[(wn +      lr) * LPC + ko];
        bf16x8 b1 = *(bf16x8*)&Bs[(wn + 16 + lr) * LPC + ko];
        acc2[0] = __builtin_amdgcn_mfma_f32_16x16x32_bf16(a, b0, acc2[0], 0, 0, 0);
        acc2[1] = __builtin_amdgcn_mfma_f32_16x16x32_bf16(a, b1, acc2[1], 0, 0, 0);
    }

    #pragma unroll
    for (int j = 0; j < 2; j++) {
        const int gn = n0 + wn + 16 * j + lr;
        const float bv = bias[gn];
        #pragma unroll
        for (int rr = 0; rr < 4; rr++) {
            const int gm = m0 + wm + lq * 4 + rr;
            out[gm * OUT_DIMS + gn] = acc2[j][rr] + bv;
        }
    }
}

extern "C" void kernel_launch(void* const* d_in, const int* in_sizes, int n_in,
                              void* d_out, int out_size, void* d_ws, size_t ws_size,
                              hipStream_t stream)
{
    const float* modulations = (const float*)d_in[0]; // [1024, 256]
    const float* x           = (const float*)d_in[1]; // [1024, 512]
    const float* weight      = (const float*)d_in[2]; // [512, 512]
    const float* bias        = (const float*)d_in[3]; // [512]
    const float* mod_w       = (const float*)d_in[4]; // [512, 256]
    const float* mod_b       = (const float*)d_in[5]; // [512]
    float* out = (float*)d_out;                       // [1024, 512]
    ush* t_bf = (ush*)d_ws;                           // 1 MB

    void* args[] = {
        (void*)&modulations, (void*)&x, (void*)&weight, (void*)&bias,
        (void*)&mod_w, (void*)&mod_b, (void*)&t_bf, (void*)&out
    };
    hipLaunchCooperativeKernel((const void*)fused_all, dim3(8, 32), dim3(256),
                               args, 0, stream);
}